// Round 3
// baseline (395.939 us; speedup 1.0000x reference)
//
#include <hip/hip_runtime.h>

// out[N,32] = scatter_add over edges e: values[e] * x[cols[e], :] into row rows[e]
//
// Pipeline (bucket = row >> 7, 128 rows/bucket, NB = ceil(N/128) = 782):
//   k1 hist : per-WG LDS histogram of buckets -> global bucket counts
//   k2 scan : single-WG exclusive scan (782 entries) -> bucket_start, cursor
//   k3 bin  : WG-aggregated scatter of packed [val:32|col:17|rloc:7] records
//             into per-bucket contiguous runs (coalesced via one-XCD locality)
//   k4 spmm : one WG per bucket; LDS f32-atomic accumulate acc[128][33];
//             coalesced block write of out. No global atomics, no memset.
//
// indices: d_in[0] = int[2*NNZ], values: d_in[1] = float[NNZ], x: d_in[2] = float[N*32]

#define D 32
#define BSHIFT 7
#define RPB 128                 // rows per bucket = 1 << BSHIFT
#define NB_MAX 1024
#define CHUNK 8192              // edges per workgroup in hist/bin

// ---------- k1: bucket histogram with LDS pre-aggregation ----------
__global__ __launch_bounds__(256) void hist_kernel(
    const int* __restrict__ idx, int* __restrict__ gcnt, int nnz, int nb)
{
    __shared__ int lcnt[NB_MAX];
    for (int i = threadIdx.x; i < nb; i += 256) lcnt[i] = 0;
    __syncthreads();
    int base = blockIdx.x * CHUNK;
    int end = min(base + CHUNK, nnz);
    for (int e = base + threadIdx.x; e < end; e += 256)
        atomicAdd(&lcnt[idx[e] >> BSHIFT], 1);
    __syncthreads();
    for (int i = threadIdx.x; i < nb; i += 256) {
        int c = lcnt[i];
        if (c) atomicAdd(&gcnt[i], c);
    }
}

// ---------- k2: exclusive scan of bucket counts (single 1024-thread WG) ----------
__global__ __launch_bounds__(1024) void scan_kernel(
    const int* __restrict__ gcnt, int* __restrict__ start,
    int* __restrict__ gcursor, int nb)
{
    __shared__ int sm[1024];
    int v = (threadIdx.x < nb) ? gcnt[threadIdx.x] : 0;
    sm[threadIdx.x] = v;
    __syncthreads();
    for (int off = 1; off < 1024; off <<= 1) {
        int t = sm[threadIdx.x];
        int u = (threadIdx.x >= off) ? sm[threadIdx.x - off] : 0;
        __syncthreads();
        sm[threadIdx.x] = t + u;
        __syncthreads();
    }
    if (threadIdx.x < nb) {
        int ex = sm[threadIdx.x] - v;
        start[threadIdx.x] = ex;
        gcursor[threadIdx.x] = ex;
    }
    if (threadIdx.x == 1023) start[nb] = sm[1023];
}

// ---------- k3: WG-aggregated bin scatter ----------
__global__ __launch_bounds__(256) void bin_kernel(
    const int* __restrict__ idx, const float* __restrict__ vals,
    int* __restrict__ gcursor, unsigned long long* __restrict__ packed,
    int nnz, int nb)
{
    __shared__ int lcnt[NB_MAX];
    __shared__ int lbase[NB_MAX];
    int base = blockIdx.x * CHUNK;
    int end = min(base + CHUNK, nnz);
    for (int i = threadIdx.x; i < nb; i += 256) lcnt[i] = 0;
    __syncthreads();
    for (int e = base + threadIdx.x; e < end; e += 256)
        atomicAdd(&lcnt[idx[e] >> BSHIFT], 1);
    __syncthreads();
    for (int i = threadIdx.x; i < nb; i += 256) {
        int c = lcnt[i];
        lbase[i] = c ? atomicAdd(&gcursor[i], c) : 0;
        lcnt[i] = 0;                       // reuse as intra-WG cursor
    }
    __syncthreads();
    for (int e = base + threadIdx.x; e < end; e += 256) {
        int r = idx[e];
        int b = r >> BSHIFT;
        int pos = lbase[b] + atomicAdd(&lcnt[b], 1);
        unsigned c = (unsigned)idx[nnz + e];
        unsigned vb = __float_as_uint(vals[e]);
        packed[pos] = ((unsigned long long)vb << 32)
                    | ((unsigned long long)c << BSHIFT) | (unsigned)(r & (RPB - 1));
    }
}

// ---------- k4: bucket SpMM with LDS accumulation ----------
__global__ __launch_bounds__(256) void spmm_bucket_kernel(
    const int* __restrict__ bucket_start,
    const unsigned long long* __restrict__ packed,
    const float* __restrict__ x, float* __restrict__ out, int N)
{
    __shared__ float acc[RPB * 33];    // +1 pad: breaks 32-bank aliasing
    for (int i = threadIdx.x; i < RPB * 33; i += 256) acc[i] = 0.f;
    __syncthreads();

    int b = blockIdx.x;
    int s = bucket_start[b];
    int e = bucket_start[b + 1];
    int g = threadIdx.x >> 3;          // 32 edge-groups of 8 lanes
    int q = threadIdx.x & 7;           // 4 columns each
    const float4* __restrict__ x4 = reinterpret_cast<const float4*>(x);

    int k = s + g;
    for (; k + 32 < e; k += 64) {      // 2x unroll for MLP
        unsigned long long p0 = packed[k];
        unsigned long long p1 = packed[k + 32];
        int   rl0 = (int)(p0 & (RPB - 1));
        int   c0  = (int)((p0 >> BSHIFT) & 0x1ffff);
        float v0  = __uint_as_float((unsigned)(p0 >> 32));
        int   rl1 = (int)(p1 & (RPB - 1));
        int   c1  = (int)((p1 >> BSHIFT) & 0x1ffff);
        float v1  = __uint_as_float((unsigned)(p1 >> 32));
        float4 a0 = x4[(size_t)c0 * (D / 4) + q];
        float4 a1 = x4[(size_t)c1 * (D / 4) + q];
        float* d0 = &acc[rl0 * 33 + q * 4];
        atomicAdd(d0 + 0, v0 * a0.x);
        atomicAdd(d0 + 1, v0 * a0.y);
        atomicAdd(d0 + 2, v0 * a0.z);
        atomicAdd(d0 + 3, v0 * a0.w);
        float* d1 = &acc[rl1 * 33 + q * 4];
        atomicAdd(d1 + 0, v1 * a1.x);
        atomicAdd(d1 + 1, v1 * a1.y);
        atomicAdd(d1 + 2, v1 * a1.z);
        atomicAdd(d1 + 3, v1 * a1.w);
    }
    for (; k < e; k += 32) {
        unsigned long long p = packed[k];
        int   rl = (int)(p & (RPB - 1));
        int   c  = (int)((p >> BSHIFT) & 0x1ffff);
        float v  = __uint_as_float((unsigned)(p >> 32));
        float4 a = x4[(size_t)c * (D / 4) + q];
        float* d = &acc[rl * 33 + q * 4];
        atomicAdd(d + 0, v * a.x);
        atomicAdd(d + 1, v * a.y);
        atomicAdd(d + 2, v * a.z);
        atomicAdd(d + 3, v * a.w);
    }
    __syncthreads();

    int row0 = b << BSHIFT;
    int lim = min(RPB, N - row0);
    for (int i = threadIdx.x; i < lim * D; i += 256)
        out[(size_t)row0 * D + i] = acc[(i >> 5) * 33 + (i & 31)];
}

// ---------- fallback: direct atomic scatter (round-1) ----------
__global__ __launch_bounds__(256) void spmm_scatter_kernel(
    const int* __restrict__ idx, const float* __restrict__ vals,
    const float* __restrict__ x, float* __restrict__ out, int nnz)
{
    int t = blockIdx.x * blockDim.x + threadIdx.x;
    int e = t >> 3;
    int q = t & 7;
    if (e >= nnz) return;
    int r = idx[e];
    int c = idx[nnz + e];
    float v = vals[e];
    const float4 xv = reinterpret_cast<const float4*>(x)[(size_t)c * (D / 4) + q];
    float* o = out + (size_t)r * D + q * 4;
    atomicAdd(o + 0, v * xv.x);
    atomicAdd(o + 1, v * xv.y);
    atomicAdd(o + 2, v * xv.z);
    atomicAdd(o + 3, v * xv.w);
}

static inline size_t align256(size_t v) { return (v + 255) & ~(size_t)255; }

extern "C" void kernel_launch(void* const* d_in, const int* in_sizes, int n_in,
                              void* d_out, int out_size, void* d_ws, size_t ws_size,
                              hipStream_t stream)
{
    const int* idx   = (const int*)d_in[0];
    const float* val = (const float*)d_in[1];
    const float* x   = (const float*)d_in[2];
    float* out       = (float*)d_out;

    const int nnz = in_sizes[1];
    const int N   = out_size / D;
    const int nb  = (N + RPB - 1) >> BSHIFT;

    size_t off_cnt    = 0;
    size_t off_start  = align256(off_cnt    + (size_t)nb * 4);
    size_t off_cursor = align256(off_start  + (size_t)(nb + 1) * 4);
    size_t off_packed = align256(off_cursor + (size_t)nb * 4);
    size_t ws_needed  = off_packed + (size_t)nnz * 8;

    // col must fit 17 bits, nb must fit scan width
    if (ws_size < ws_needed || nb > NB_MAX || N > 131072) {
        hipMemsetAsync(d_out, 0, (size_t)out_size * sizeof(float), stream);
        const long long total = (long long)nnz * 8;
        spmm_scatter_kernel<<<(int)((total + 255) / 256), 256, 0, stream>>>(
            idx, val, x, out, nnz);
        return;
    }

    char* ws = (char*)d_ws;
    int* gcnt    = (int*)(ws + off_cnt);
    int* start   = (int*)(ws + off_start);
    int* gcursor = (int*)(ws + off_cursor);
    unsigned long long* packed = (unsigned long long*)(ws + off_packed);

    hipMemsetAsync(gcnt, 0, (size_t)nb * 4, stream);

    const int nchunk = (nnz + CHUNK - 1) / CHUNK;
    hist_kernel<<<nchunk, 256, 0, stream>>>(idx, gcnt, nnz, nb);
    scan_kernel<<<1, 1024, 0, stream>>>(gcnt, start, gcursor, nb);
    bin_kernel<<<nchunk, 256, 0, stream>>>(idx, val, gcursor, packed, nnz, nb);
    spmm_bucket_kernel<<<nb, 256, 0, stream>>>(start, packed, x, out, N);
}

// Round 4
// 338.741 us; speedup vs baseline: 1.1689x; 1.1689x over previous
//
#include <hip/hip_runtime.h>

// out[N,32] = scatter_add over edges e: values[e] * x[cols[e], :] into row rows[e]
//
// Pipeline (bucket = row >> 7, 128 rows/bucket, NB = ceil(N/128) = 782):
//   k1 hist : per-WG LDS histogram of buckets -> global bucket counts
//   k2 scan : single-WG exclusive scan (782 entries) -> bucket_start, cursor
//   k3 bin  : WG-aggregated scatter of packed [val:32|col:17|rloc:7] records
//             into per-bucket contiguous runs (runs ~84B -> write-coalesced)
//   k4 spmm : FOUR WGs per bucket; WG j streams the bucket's packed run and
//             accumulates only rows [32j,32j+32) into acc[32][33] LDS, then
//             writes its 32x32 out block coalesced. No global atomics.
//
// indices: d_in[0] = int[2*NNZ], values: d_in[1] = float[NNZ], x: d_in[2] = float[N*32]

#define D 32
#define BSHIFT 7
#define RPB 128                 // rows per bucket = 1 << BSHIFT
#define SUB 32                  // rows per spmm workgroup
#define NSUB (RPB / SUB)        // spmm WGs per bucket = 4
#define NB_MAX 1024
#define CHUNK 8192              // edges per workgroup in hist/bin

// ---------- k1: bucket histogram with LDS pre-aggregation ----------
__global__ __launch_bounds__(256) void hist_kernel(
    const int* __restrict__ idx, int* __restrict__ gcnt, int nnz, int nb)
{
    __shared__ int lcnt[NB_MAX];
    for (int i = threadIdx.x; i < nb; i += 256) lcnt[i] = 0;
    __syncthreads();
    int base = blockIdx.x * CHUNK;
    int end = min(base + CHUNK, nnz);
    for (int e = base + threadIdx.x; e < end; e += 256)
        atomicAdd(&lcnt[idx[e] >> BSHIFT], 1);
    __syncthreads();
    for (int i = threadIdx.x; i < nb; i += 256) {
        int c = lcnt[i];
        if (c) atomicAdd(&gcnt[i], c);
    }
}

// ---------- k2: exclusive scan of bucket counts (single 1024-thread WG) ----------
__global__ __launch_bounds__(1024) void scan_kernel(
    const int* __restrict__ gcnt, int* __restrict__ start,
    int* __restrict__ gcursor, int nb)
{
    __shared__ int sm[1024];
    int v = (threadIdx.x < nb) ? gcnt[threadIdx.x] : 0;
    sm[threadIdx.x] = v;
    __syncthreads();
    for (int off = 1; off < 1024; off <<= 1) {
        int t = sm[threadIdx.x];
        int u = (threadIdx.x >= off) ? sm[threadIdx.x - off] : 0;
        __syncthreads();
        sm[threadIdx.x] = t + u;
        __syncthreads();
    }
    if (threadIdx.x < nb) {
        int ex = sm[threadIdx.x] - v;
        start[threadIdx.x] = ex;
        gcursor[threadIdx.x] = ex;
    }
    if (threadIdx.x == 1023) start[nb] = sm[1023];
}

// ---------- k3: WG-aggregated bin scatter ----------
__global__ __launch_bounds__(256) void bin_kernel(
    const int* __restrict__ idx, const float* __restrict__ vals,
    int* __restrict__ gcursor, unsigned long long* __restrict__ packed,
    int nnz, int nb)
{
    __shared__ int lcnt[NB_MAX];
    __shared__ int lbase[NB_MAX];
    int base = blockIdx.x * CHUNK;
    int end = min(base + CHUNK, nnz);
    for (int i = threadIdx.x; i < nb; i += 256) lcnt[i] = 0;
    __syncthreads();
    for (int e = base + threadIdx.x; e < end; e += 256)
        atomicAdd(&lcnt[idx[e] >> BSHIFT], 1);
    __syncthreads();
    for (int i = threadIdx.x; i < nb; i += 256) {
        int c = lcnt[i];
        lbase[i] = c ? atomicAdd(&gcursor[i], c) : 0;
        lcnt[i] = 0;                       // reuse as intra-WG cursor
    }
    __syncthreads();
    for (int e = base + threadIdx.x; e < end; e += 256) {
        int r = idx[e];
        int b = r >> BSHIFT;
        int pos = lbase[b] + atomicAdd(&lcnt[b], 1);
        unsigned c = (unsigned)idx[nnz + e];
        unsigned vb = __float_as_uint(vals[e]);
        packed[pos] = ((unsigned long long)vb << 32)
                    | ((unsigned long long)c << BSHIFT) | (unsigned)(r & (RPB - 1));
    }
}

// ---------- k4: sub-bucket SpMM — 4 WGs per bucket, row-filtered ----------
__global__ __launch_bounds__(256) void spmm_sub_kernel(
    const int* __restrict__ bucket_start,
    const unsigned long long* __restrict__ packed,
    const float* __restrict__ x, float* __restrict__ out, int N)
{
    __shared__ float acc[SUB * 33];        // +1 pad breaks bank aliasing
    for (int i = threadIdx.x; i < SUB * 33; i += 256) acc[i] = 0.f;
    __syncthreads();

    int wg  = blockIdx.x;
    int b   = wg >> 2;                     // bucket
    int rlo = (wg & 3) * SUB;              // sub-bucket row base
    int s = bucket_start[b];
    int e = bucket_start[b + 1];
    int g = threadIdx.x >> 3;              // 32 edge-groups of 8 lanes
    int q = threadIdx.x & 7;               // 4 columns each
    const float4* __restrict__ x4 = reinterpret_cast<const float4*>(x);

    int k = s + g;
    for (; k + 32 < e; k += 64) {          // 2x unroll: two packed loads in flight
        unsigned long long p0 = packed[k];
        unsigned long long p1 = packed[k + 32];
        int rl0 = (int)(p0 & (RPB - 1)) - rlo;
        int rl1 = (int)(p1 & (RPB - 1)) - rlo;
        if ((unsigned)rl0 < SUB) {
            int   c = (int)((p0 >> BSHIFT) & 0x1ffff);
            float v = __uint_as_float((unsigned)(p0 >> 32));
            float4 a = x4[(size_t)c * (D / 4) + q];
            float* d = &acc[rl0 * 33 + q * 4];
            atomicAdd(d + 0, v * a.x);
            atomicAdd(d + 1, v * a.y);
            atomicAdd(d + 2, v * a.z);
            atomicAdd(d + 3, v * a.w);
        }
        if ((unsigned)rl1 < SUB) {
            int   c = (int)((p1 >> BSHIFT) & 0x1ffff);
            float v = __uint_as_float((unsigned)(p1 >> 32));
            float4 a = x4[(size_t)c * (D / 4) + q];
            float* d = &acc[rl1 * 33 + q * 4];
            atomicAdd(d + 0, v * a.x);
            atomicAdd(d + 1, v * a.y);
            atomicAdd(d + 2, v * a.z);
            atomicAdd(d + 3, v * a.w);
        }
    }
    for (; k < e; k += 32) {
        unsigned long long p = packed[k];
        int rl = (int)(p & (RPB - 1)) - rlo;
        if ((unsigned)rl < SUB) {
            int   c = (int)((p >> BSHIFT) & 0x1ffff);
            float v = __uint_as_float((unsigned)(p >> 32));
            float4 a = x4[(size_t)c * (D / 4) + q];
            float* d = &acc[rl * 33 + q * 4];
            atomicAdd(d + 0, v * a.x);
            atomicAdd(d + 1, v * a.y);
            atomicAdd(d + 2, v * a.z);
            atomicAdd(d + 3, v * a.w);
        }
    }
    __syncthreads();

    int row0 = (b << BSHIFT) + rlo;
    int lim = min(SUB, N - row0);
    if (lim > 0)
        for (int i = threadIdx.x; i < lim * D; i += 256)
            out[(size_t)row0 * D + i] = acc[(i >> 5) * 33 + (i & 31)];
}

// ---------- fallback: direct atomic scatter (round-1) ----------
__global__ __launch_bounds__(256) void spmm_scatter_kernel(
    const int* __restrict__ idx, const float* __restrict__ vals,
    const float* __restrict__ x, float* __restrict__ out, int nnz)
{
    int t = blockIdx.x * blockDim.x + threadIdx.x;
    int e = t >> 3;
    int q = t & 7;
    if (e >= nnz) return;
    int r = idx[e];
    int c = idx[nnz + e];
    float v = vals[e];
    const float4 xv = reinterpret_cast<const float4*>(x)[(size_t)c * (D / 4) + q];
    float* o = out + (size_t)r * D + q * 4;
    atomicAdd(o + 0, v * xv.x);
    atomicAdd(o + 1, v * xv.y);
    atomicAdd(o + 2, v * xv.z);
    atomicAdd(o + 3, v * xv.w);
}

static inline size_t align256(size_t v) { return (v + 255) & ~(size_t)255; }

extern "C" void kernel_launch(void* const* d_in, const int* in_sizes, int n_in,
                              void* d_out, int out_size, void* d_ws, size_t ws_size,
                              hipStream_t stream)
{
    const int* idx   = (const int*)d_in[0];
    const float* val = (const float*)d_in[1];
    const float* x   = (const float*)d_in[2];
    float* out       = (float*)d_out;

    const int nnz = in_sizes[1];
    const int N   = out_size / D;
    const int nb  = (N + RPB - 1) >> BSHIFT;

    size_t off_cnt    = 0;
    size_t off_start  = align256(off_cnt    + (size_t)nb * 4);
    size_t off_cursor = align256(off_start  + (size_t)(nb + 1) * 4);
    size_t off_packed = align256(off_cursor + (size_t)nb * 4);
    size_t ws_needed  = off_packed + (size_t)nnz * 8;

    // col must fit 17 bits, nb must fit scan width
    if (ws_size < ws_needed || nb > NB_MAX || N > 131072) {
        hipMemsetAsync(d_out, 0, (size_t)out_size * sizeof(float), stream);
        const long long total = (long long)nnz * 8;
        spmm_scatter_kernel<<<(int)((total + 255) / 256), 256, 0, stream>>>(
            idx, val, x, out, nnz);
        return;
    }

    char* ws = (char*)d_ws;
    int* gcnt    = (int*)(ws + off_cnt);
    int* start   = (int*)(ws + off_start);
    int* gcursor = (int*)(ws + off_cursor);
    unsigned long long* packed = (unsigned long long*)(ws + off_packed);

    hipMemsetAsync(gcnt, 0, (size_t)nb * 4, stream);

    const int nchunk = (nnz + CHUNK - 1) / CHUNK;
    hist_kernel<<<nchunk, 256, 0, stream>>>(idx, gcnt, nnz, nb);
    scan_kernel<<<1, 1024, 0, stream>>>(gcnt, start, gcursor, nb);
    bin_kernel<<<nchunk, 256, 0, stream>>>(idx, val, gcursor, packed, nnz, nb);
    spmm_sub_kernel<<<nb * NSUB, 256, 0, stream>>>(start, packed, x, out, N);
}